// Round 15
// baseline (66.467 us; speedup 1.0000x reference)
//
#include <hip/hip_runtime.h>

// Fused LSTM-heads + 4-layer MLP on the MATRIX pipe.
// r15: TWO independent 64-row tiles PER WAVE (software-pipelined chains).
// 256-thread block = 4 wave-slices x 2 tiles = 512 rows/block, 64KB LDS.
// Each phase issued for T0 then T1 -> two dependence-disjoint chains per
// wave; while T0 waits on lgkmcnt, T1's MFMAs issue. LSTM scalar-pipe
// weight loads amortize over both tiles.
// Layout/opt set otherwise identical to r14: K-permuted b64 spill pairing,
// pre-packed B-fragments, bias-as-MFMA-C, pkrelu, fused-rcp sigtanh,
// pre-sigmoid staging + block-coalesced store epilogue.

#define BLK  256
#define WPB  4
#define TPW  2
#define WSTR 4096   // per-wave LDS u32 (2 tiles x 2048)
#define KSEQ 11

typedef _Float16 h2   __attribute__((ext_vector_type(2)));
typedef _Float16 h8   __attribute__((ext_vector_type(8)));
typedef float    f4   __attribute__((ext_vector_type(4)));
typedef unsigned u16v __attribute__((ext_vector_type(16)));

#define N_FRAG_U32 6144   // 24 tiles * 64 lanes * 4 u32 (f16 pairs)
#define N_BIAS     768    // 12 bias-tiles * 64 lanes (f32 bits)
#define N_LSTM     288    // 12 * 24 floats (W_ih 16 + folded bias 8 per k)

__device__ __align__(16) float    g_lstm[N_LSTM];
__device__ __align__(16) unsigned g_frag[N_FRAG_U32];
__device__ __align__(16) unsigned g_bias[N_BIAS];

__device__ __forceinline__ h2 pk(float a, float b) {
    auto r = __builtin_amdgcn_cvt_pkrtz(a, b);
    union { decltype(r) f; h2 h; } c; c.f = r; return c.h;
}
__device__ __forceinline__ unsigned as_u32(h2 h) {
    union { h2 h; unsigned u; } c; c.h = h; return c.u;
}
__device__ __forceinline__ float uf(unsigned u) {
    union { unsigned u; float f; } c; c.u = u; return c.f;
}
__device__ __forceinline__ unsigned pkrelu(float a, float b) {   // pack then v_pk_max_f16
    h2 p = pk(a, b);
    h2 z = {(_Float16)0.0f, (_Float16)0.0f};
    h2 r = __builtin_elementwise_max(p, z);
    return as_u32(r);
}
__device__ __forceinline__ float fast_exp(float x) {
#if __has_builtin(__builtin_amdgcn_exp2f)
    return __builtin_amdgcn_exp2f(x * 1.44269504088896340736f);
#else
    return __expf(x);
#endif
}
__device__ __forceinline__ float fast_rcp(float x) {
#if __has_builtin(__builtin_amdgcn_rcpf)
    return __builtin_amdgcn_rcpf(x);
#else
    return 1.0f / x;
#endif
}
__device__ __forceinline__ float sig1(float x)  { return fast_rcp(1.0f + fast_exp(-x)); }

// sig(a) * tanh(b) with a single rcp
__device__ __forceinline__ float sigtanh(float a, float b) {
    float ea = fast_exp(-a);
    float eb = fast_exp(2.0f * b);
    return (eb - 1.0f) * fast_rcp((1.0f + ea) * (eb + 1.0f));
}

// scalar-pipe load of 48 u32 (LSTM params for a k-pair); waitcnt fused in-block
__device__ __forceinline__ void sload3(const unsigned* p, u16v& c0, u16v& c1, u16v& c2) {
    asm volatile("s_load_dwordx16 %0, %3, 0x0\n\t"
                 "s_load_dwordx16 %1, %3, 0x40\n\t"
                 "s_load_dwordx16 %2, %3, 0x80\n\t"
                 "s_waitcnt lgkmcnt(0)"
                 : "=&s"(c0), "=&s"(c1), "=&s"(c2) : "s"(p));
}
__device__ __forceinline__ unsigned pick48(const u16v& c0, const u16v& c1, const u16v& c2, int j) {
    return j < 16 ? c0[j] : (j < 32 ? c1[j - 16] : c2[j - 32]);
}

__device__ __forceinline__ void lstm_one(const u16v& c0, const u16v& c1, const u16v& c2, int base,
                                         float2 x, h2& outp)
{
    float w0  = uf(pick48(c0, c1, c2, base + 0)),  w1  = uf(pick48(c0, c1, c2, base + 1));
    float w2  = uf(pick48(c0, c1, c2, base + 2)),  w3  = uf(pick48(c0, c1, c2, base + 3));
    float w8  = uf(pick48(c0, c1, c2, base + 8)),  w9  = uf(pick48(c0, c1, c2, base + 9));
    float w10 = uf(pick48(c0, c1, c2, base + 10)), w11 = uf(pick48(c0, c1, c2, base + 11));
    float w12 = uf(pick48(c0, c1, c2, base + 12)), w13 = uf(pick48(c0, c1, c2, base + 13));
    float w14 = uf(pick48(c0, c1, c2, base + 14)), w15 = uf(pick48(c0, c1, c2, base + 15));
    float B0  = uf(pick48(c0, c1, c2, base + 16)), B1v = uf(pick48(c0, c1, c2, base + 17));
    float B4  = uf(pick48(c0, c1, c2, base + 20)), B5  = uf(pick48(c0, c1, c2, base + 21));
    float B6  = uf(pick48(c0, c1, c2, base + 22)), B7  = uf(pick48(c0, c1, c2, base + 23));

    float x0 = x.x, x1 = x.y;
    float gi0 = B0  + x0 * w0  + x1 * w1;
    float gi1 = B1v + x0 * w2  + x1 * w3;
    float gg0 = B4  + x0 * w8  + x1 * w9;
    float gg1 = B5  + x0 * w10 + x1 * w11;
    float go0 = B6  + x0 * w12 + x1 * w13;
    float go1 = B7  + x0 * w14 + x1 * w15;
    float cc0 = sigtanh(gi0, gg0);
    float cc1 = sigtanh(gi1, gg1);
    float h0  = sigtanh(go0, cc0);
    float h1  = sigtanh(go1, cc1);
    outp = pk(h0, h1);
}

// ---- prep: pack B-fragments, bias tiles, LSTM params (unchanged) ----
__global__ void prep_weights(const float* __restrict__ W_ih, const float* __restrict__ b_ih,
                             const float* __restrict__ b_hh,
                             const float* __restrict__ W1, const float* __restrict__ b1,
                             const float* __restrict__ W2, const float* __restrict__ b2,
                             const float* __restrict__ W3, const float* __restrict__ b3,
                             const float* __restrict__ W4, const float* __restrict__ b4)
{
    const int gid = blockIdx.x * blockDim.x + threadIdx.x;
    const int gs  = gridDim.x * blockDim.x;

    for (int i = gid; i < N_FRAG_U32; i += gs) {
        int t = i >> 8, rlo = i & 255;
        int lane = rlo >> 2, j = rlo & 3;
        const float* W; int N, K, ld, ks, nt;
        if (t < 8)       { W = W1; N = 51; K = 34; ld = 34; ks = t >> 2;     nt = t & 3; }
        else if (t < 16) { W = W2; N = 51; K = 51; ld = 51; ks = (t-8) >> 2; nt = (t-8) & 3; }
        else if (t < 22) { W = W3; N = 34; K = 51; ld = 51; ks = (t-16) / 3; nt = (t-16) % 3; }
        else             { W = W4; N = 5;  K = 34; ld = 34; ks = t - 22;     nt = 0; }
        int n = nt * 16 + (lane & 15);
        int p = ks * 16 + (lane >> 4) * 4 + j;
        int k_lo, k_hi;
        if (t < 8) { k_lo = 2 * p;                              k_hi = k_lo + 1;  }
        else       { k_lo = (p & 1) ? 32 + (p >> 1) : (p >> 1); k_hi = k_lo + 16; }
        float a = (n < N && k_lo < K) ? W[n * ld + k_lo] : 0.f;
        float b = (n < N && k_hi < K) ? W[n * ld + k_hi] : 0.f;
        g_frag[i] = as_u32(pk(a, b));
    }
    for (int i = gid; i < N_BIAS; i += gs) {
        int bt = i >> 6, lane = i & 63;
        const float* bv; int N, nt;
        if (bt < 4)       { bv = b1; N = 51; nt = bt; }
        else if (bt < 8)  { bv = b2; N = 51; nt = bt - 4; }
        else if (bt < 11) { bv = b3; N = 34; nt = bt - 8; }
        else              { bv = b4; N = 5;  nt = 0; }
        int col = nt * 16 + (lane & 15);
        g_bias[i] = __float_as_uint(col < N ? bv[col] : 0.f);
    }
    for (int i = gid; i < N_LSTM; i += gs) {
        int k = i / 24, cc = i - k * 24;
        float v = 0.f;
        if (k < KSEQ) v = (cc < 16) ? W_ih[k * 16 + cc]
                                    : b_ih[k * 8 + (cc - 16)] + b_hh[k * 8 + (cc - 16)];
        g_lstm[i] = v;
    }
}

// ---- main kernel helpers (unchanged from r14) ----
__device__ __forceinline__ h8 load_frag(int tile, int l) {
    union { uint4 u; h8 h; } u;
    u.u = *(const uint4*)&g_frag[tile * 256 + l * 4];
    return u.h;
}

__device__ __forceinline__ void read_afrags(h8 (&a)[4][2], const unsigned* my, int l)
{
    const int c = l & 15, g = l >> 4;
    const int mrd = (c & 7) << 2;
    #pragma unroll
    for (int mt = 0; mt < 4; ++mt)
      #pragma unroll
      for (int ks = 0; ks < 2; ++ks) {
        int idx = (mt * 16 + c) * 32 + ((ks * 16 + g * 4) ^ mrd);
        union { uint4 u; h8 h; } u;
        u.u = *(const uint4*)&my[idx];
        a[mt][ks] = u.h;
      }
}

template<int NT, int TBASE, int BBASE>
__device__ __forceinline__ void layer_mfma(const h8 (&a)[4][2], f4 (&acc)[4][4],
                                           const float (&bs)[12], int l)
{
    f4 bias4[NT];
    #pragma unroll
    for (int nt = 0; nt < NT; ++nt) {
        float b = bs[BBASE + nt];
        bias4[nt] = f4{b, b, b, b};
    }
    #pragma unroll
    for (int nt = 0; nt < NT; ++nt) {                    // ks = 0: C = bias
        h8 bf = load_frag(TBASE + nt, l);
        #pragma unroll
        for (int mt = 0; mt < 4; ++mt)
          acc[mt][nt] = __builtin_amdgcn_mfma_f32_16x16x32_f16(a[mt][0], bf, bias4[nt], 0, 0, 0);
    }
    #pragma unroll
    for (int nt = 0; nt < NT; ++nt) {                    // ks = 1: accumulate
        h8 bf = load_frag(TBASE + NT + nt, l);
        #pragma unroll
        for (int mt = 0; mt < 4; ++mt)
          acc[mt][nt] = __builtin_amdgcn_mfma_f32_16x16x32_f16(a[mt][1], bf, acc[mt][nt], 0, 0, 0);
    }
}

template<int NT>
__device__ __forceinline__ void spill_act(const f4 (&acc)[4][4], unsigned* my, int l)
{
    const int g = l >> 4, c = l & 15;
    #pragma unroll
    for (int mt = 0; mt < 4; ++mt)
      #pragma unroll
      for (int r = 0; r < 4; ++r) {
        const int row  = mt * 16 + g * 4 + r;
        const int rowm = (row & 7) << 2;
        uint2 q;
        q.x = pkrelu(acc[mt][0][r], acc[mt][1][r]);
        float d3 = (NT >= 4) ? acc[mt][3][r] : 0.f;
        q.y = pkrelu(acc[mt][2][r], d3);
        *(uint2*)&my[row * 32 + ((2 * c) ^ rowm)] = q;
      }
}

// stage0: write full activation row (row = l), sequential pairs, swizzled
__device__ __forceinline__ void stage0(const unsigned (&cp)[32], unsigned* my, int l)
{
    const int m = (l & 7) << 2;
    #pragma unroll
    for (int ch = 0; ch < 8; ++ch) {
        uint4 q = make_uint4(cp[4*ch], cp[4*ch+1], cp[4*ch+2], cp[4*ch+3]);
        *(uint4*)&my[l * 32 + ((4 * ch) ^ m)] = q;
    }
}

__global__ __launch_bounds__(BLK, 2)
void fused_rnn_mlp(const float* __restrict__ in, float* __restrict__ out, int nrows)
{
    __shared__ unsigned act[WPB * WSTR];                 // 64 KB: 8KB x 2 tiles x 4 waves
    const int tid = threadIdx.x;
    const int w = tid >> 6, l = tid & 63;
    unsigned* my0 = &act[w * WSTR];
    unsigned* my1 = my0 + 2048;
    const long long rb = (long long)blockIdx.x * (BLK * TPW);   // 512 rows/block
    if (rb + BLK * TPW > nrows) return;
    const long long rw0 = rb + w * 128;
    const long long rw1 = rw0 + 64;

    // bias tiles (12 coalesced dwords, shared by both tiles)
    float bs[12];
    #pragma unroll
    for (int i = 0; i < 12; ++i) bs[i] = uf(g_bias[i * 64 + l]);

    // own rows for both tiles (8B-aligned, 136B stride)
    float2 x0[17], x1[17];
    {
        const float2* rp0 = (const float2*)(in + (rw0 + l) * 34);
        const float2* rp1 = (const float2*)(in + (rw1 + l) * 34);
        #pragma unroll
        for (int i = 0; i < 17; ++i) { x0[i] = rp0[i]; x1[i] = rp1[i]; }
    }

    // LSTM heads: scalar-pipe weights amortized over BOTH tiles
    unsigned cp0[32], cp1[32];
    #pragma unroll
    for (int kp = 0; kp < 6; ++kp) {
        u16v c0, c1, c2;
        sload3((const unsigned*)&g_lstm[kp * 48], c0, c1, c2);
        h2 h;
        lstm_one(c0, c1, c2, 0, x0[2 * kp], h); cp0[2 * kp] = as_u32(h);
        lstm_one(c0, c1, c2, 0, x1[2 * kp], h); cp1[2 * kp] = as_u32(h);
        if (kp < 5) {
            lstm_one(c0, c1, c2, 24, x0[2 * kp + 1], h); cp0[2 * kp + 1] = as_u32(h);
            lstm_one(c0, c1, c2, 24, x1[2 * kp + 1], h); cp1[2 * kp + 1] = as_u32(h);
        }
    }
    #pragma unroll
    for (int t = 0; t < 6; ++t) {
        cp0[11 + t] = as_u32(pk(x0[11 + t].x, x0[11 + t].y));
        cp1[11 + t] = as_u32(pk(x1[11 + t].x, x1[11 + t].y));
    }
    #pragma unroll
    for (int t = 17; t < 32; ++t) { cp0[t] = 0u; cp1[t] = 0u; }

    stage0(cp0, my0, l);
    stage0(cp1, my1, l);

    h8 a0[4][2], a1[4][2];
    f4 acc0[4][4], acc1[4][4];

    // L1: 34 -> 51  (phases issued T0 then T1: two independent chains)
    read_afrags(a0, my0, l);           read_afrags(a1, my1, l);
    layer_mfma<4, 0, 0>(a0, acc0, bs, l);  layer_mfma<4, 0, 0>(a1, acc1, bs, l);
    spill_act<4>(acc0, my0, l);        spill_act<4>(acc1, my1, l);

    // L2: 51 -> 51
    read_afrags(a0, my0, l);           read_afrags(a1, my1, l);
    layer_mfma<4, 8, 4>(a0, acc0, bs, l);  layer_mfma<4, 8, 4>(a1, acc1, bs, l);
    spill_act<4>(acc0, my0, l);        spill_act<4>(acc1, my1, l);

    // L3: 51 -> 34
    read_afrags(a0, my0, l);           read_afrags(a1, my1, l);
    layer_mfma<3, 16, 8>(a0, acc0, bs, l); layer_mfma<3, 16, 8>(a1, acc1, bs, l);
    spill_act<3>(acc0, my0, l);        spill_act<3>(acc1, my1, l);

    // L4: 34 -> 5
    read_afrags(a0, my0, l);           read_afrags(a1, my1, l);
    layer_mfma<1, 22, 11>(a0, acc0, bs, l); layer_mfma<1, 22, 11>(a1, acc1, bs, l);

    // stage PRE-sigmoid f32 into own (now dead) act regions, 9-padded
    {
        const int c = l & 15, g = l >> 4;
        float* po0 = (float*)my0;
        float* po1 = (float*)my1;
        if (c < 5) {
            #pragma unroll
            for (int mt = 0; mt < 4; ++mt)
              #pragma unroll
              for (int r = 0; r < 4; ++r) {
                po0[(mt * 16 + g * 4 + r) * 9 + c] = acc0[mt][0][r];
                po1[(mt * 16 + g * 4 + r) * 9 + c] = acc1[mt][0][r];
              }
        }
    }
    __syncthreads();

    // block-wide coalesced store: 2560 contiguous floats, sigmoid applied here.
    // Staged layout: row r of the block's 512 lives at u32 offset
    // (r>>6)*2048 + (r&63)*9 + c  (tile index r>>6 spans wave*2+tile).
    const long long ob = rb * 5;
    const float* pact = (const float*)act;
    #pragma unroll
    for (int it = 0; it < 10; ++it) {
        int F   = it * BLK + tid;
        int row = (F * 52429) >> 18;                     // F / 5, exact for F < 2^15
        int cc  = F - row * 5;
        out[ob + F] = sig1(pact[(row >> 6) * 2048 + (row & 63) * 9 + cc]);
    }
}

extern "C" void kernel_launch(void* const* d_in, const int* in_sizes, int n_in,
                              void* d_out, int out_size, void* d_ws, size_t ws_size,
                              hipStream_t stream)
{
    const float* input = (const float*)d_in[0];
    const float* W_ih  = (const float*)d_in[1];
    const float* b_ih  = (const float*)d_in[2];
    const float* b_hh  = (const float*)d_in[3];
    const float* W1    = (const float*)d_in[4];
    const float* b1    = (const float*)d_in[5];
    const float* W2    = (const float*)d_in[6];
    const float* b2    = (const float*)d_in[7];
    const float* W3    = (const float*)d_in[8];
    const float* b3    = (const float*)d_in[9];
    const float* W4    = (const float*)d_in[10];
    const float* b4    = (const float*)d_in[11];
    float* out = (float*)d_out;

    int nrows = in_sizes[0] / 34;
    int grid  = nrows / (BLK * TPW);

    hipLaunchKernelGGL(prep_weights, dim3(8), dim3(256), 0, stream,
                       W_ih, b_ih, b_hh, W1, b1, W2, b2, W3, b3, W4, b4);
    hipLaunchKernelGGL(fused_rnn_mlp, dim3(grid), dim3(BLK), 0, stream,
                       input, out, nrows);
}

// Round 16
// 53.098 us; speedup vs baseline: 1.2518x; 1.2518x over previous
//
#include <hip/hip_runtime.h>

// Fused LSTM-heads + 4-layer MLP on the MATRIX pipe — SWAPPED-OPERAND form.
// Each layer computes D' = W · act^T  (A = W, B = activations^T):
//   D' lane layout: row n_out = (l>>4)*4+r + ot*16, col sample = st*16+(l&15).
// With k-permutation pi(p) = (2*(p>>5)+((p&7)>>2))*16 + ((p>>3)&3)*4 + (p&3)
// applied to BOTH the packed activations and the next layer's W columns,
// the inter-layer handoff is PURE IN-REGISTER (8 pkrelu per sample-tile):
// no spill, no ds_read, no cross-lane ops. Only L1 reads B-frags from the
// stage0 LDS tile (same verified read path as before). Bias rides the ks=0
// MFMA C operand, packed per-ROW (neuron). Epilogue: stage f32, barrier,
// block-coalesced sigmoid store.  256-thr block = 4 wave-slices, 32KB LDS.

#define BLK  256
#define WPB  4
#define KSEQ 11

typedef _Float16 h2   __attribute__((ext_vector_type(2)));
typedef _Float16 h8   __attribute__((ext_vector_type(8)));
typedef float    f4   __attribute__((ext_vector_type(4)));
typedef unsigned u16v __attribute__((ext_vector_type(16)));

#define N_FRAG_U32 6144   // 24 tiles * 64 lanes * 4 u32 (f16 pairs)
#define N_BIAS     3072   // 12 bias-tiles * 64 lanes * 4 rows (f32)
#define N_LSTM     288    // 12 * 24 floats (W_ih 16 + folded bias 8 per k)

__device__ __align__(16) float    g_lstm[N_LSTM];
__device__ __align__(16) unsigned g_frag[N_FRAG_U32];
__device__ __align__(16) float    g_bias[N_BIAS];

__device__ __forceinline__ h2 pk(float a, float b) {
    auto r = __builtin_amdgcn_cvt_pkrtz(a, b);
    union { decltype(r) f; h2 h; } c; c.f = r; return c.h;
}
__device__ __forceinline__ unsigned as_u32(h2 h) {
    union { h2 h; unsigned u; } c; c.h = h; return c.u;
}
__device__ __forceinline__ float uf(unsigned u) {
    union { unsigned u; float f; } c; c.u = u; return c.f;
}
__device__ __forceinline__ unsigned pkrelu(float a, float b) {   // pack then v_pk_max_f16
    h2 p = pk(a, b);
    h2 z = {(_Float16)0.0f, (_Float16)0.0f};
    h2 r = __builtin_elementwise_max(p, z);
    return as_u32(r);
}
__device__ __forceinline__ float fast_exp(float x) {
#if __has_builtin(__builtin_amdgcn_exp2f)
    return __builtin_amdgcn_exp2f(x * 1.44269504088896340736f);
#else
    return __expf(x);
#endif
}
__device__ __forceinline__ float fast_rcp(float x) {
#if __has_builtin(__builtin_amdgcn_rcpf)
    return __builtin_amdgcn_rcpf(x);
#else
    return 1.0f / x;
#endif
}
__device__ __forceinline__ float sig1(float x)  { return fast_rcp(1.0f + fast_exp(-x)); }

// sig(a) * tanh(b) with a single rcp
__device__ __forceinline__ float sigtanh(float a, float b) {
    float ea = fast_exp(-a);
    float eb = fast_exp(2.0f * b);
    return (eb - 1.0f) * fast_rcp((1.0f + ea) * (eb + 1.0f));
}

// scalar-pipe load of 48 u32 (LSTM params for a k-pair); waitcnt fused in-block
__device__ __forceinline__ void sload3(const unsigned* p, u16v& c0, u16v& c1, u16v& c2) {
    asm volatile("s_load_dwordx16 %0, %3, 0x0\n\t"
                 "s_load_dwordx16 %1, %3, 0x40\n\t"
                 "s_load_dwordx16 %2, %3, 0x80\n\t"
                 "s_waitcnt lgkmcnt(0)"
                 : "=&s"(c0), "=&s"(c1), "=&s"(c2) : "s"(p));
}
__device__ __forceinline__ unsigned pick48(const u16v& c0, const u16v& c1, const u16v& c2, int j) {
    return j < 16 ? c0[j] : (j < 32 ? c1[j - 16] : c2[j - 32]);
}

__device__ __forceinline__ void lstm_one(const u16v& c0, const u16v& c1, const u16v& c2, int base,
                                         float2 x, h2& outp)
{
    float w0  = uf(pick48(c0, c1, c2, base + 0)),  w1  = uf(pick48(c0, c1, c2, base + 1));
    float w2  = uf(pick48(c0, c1, c2, base + 2)),  w3  = uf(pick48(c0, c1, c2, base + 3));
    float w8  = uf(pick48(c0, c1, c2, base + 8)),  w9  = uf(pick48(c0, c1, c2, base + 9));
    float w10 = uf(pick48(c0, c1, c2, base + 10)), w11 = uf(pick48(c0, c1, c2, base + 11));
    float w12 = uf(pick48(c0, c1, c2, base + 12)), w13 = uf(pick48(c0, c1, c2, base + 13));
    float w14 = uf(pick48(c0, c1, c2, base + 14)), w15 = uf(pick48(c0, c1, c2, base + 15));
    float B0  = uf(pick48(c0, c1, c2, base + 16)), B1v = uf(pick48(c0, c1, c2, base + 17));
    float B4  = uf(pick48(c0, c1, c2, base + 20)), B5  = uf(pick48(c0, c1, c2, base + 21));
    float B6  = uf(pick48(c0, c1, c2, base + 22)), B7  = uf(pick48(c0, c1, c2, base + 23));

    float x0 = x.x, x1 = x.y;
    float gi0 = B0  + x0 * w0  + x1 * w1;
    float gi1 = B1v + x0 * w2  + x1 * w3;
    float gg0 = B4  + x0 * w8  + x1 * w9;
    float gg1 = B5  + x0 * w10 + x1 * w11;
    float go0 = B6  + x0 * w12 + x1 * w13;
    float go1 = B7  + x0 * w14 + x1 * w15;
    float cc0 = sigtanh(gi0, gg0);
    float cc1 = sigtanh(gi1, gg1);
    float h0  = sigtanh(go0, cc0);
    float h1  = sigtanh(go1, cc1);
    outp = pk(h0, h1);
}

// ---- prep: pack W as A-fragments, per-ROW bias tiles, LSTM params ----
// tile ids: L1: 0..7 = ks*4+nt | L2: 8..15 | L3: 16..21 = 16+ks*3+nt | L4: 22..23
// A-frag: lane holds W[m = nt*16+(lane&15)][k-position (lane>>4)*8 + jj of step ks].
//   L1 (input from stage0, sequential features): k = 2p, 2p+1 at pair-pos
//       p = ks*16 + (lane>>4)*4 + j  (byte-identical to the verified packing).
//   L2/L3/L4 (input from in-register pack): feature at global k-position q is
//       pi(q) = (2*(q>>5) + ((q&7)>>2))*16 + ((q>>3)&3)*4 + (q&3).
// bias tiles (per-row): g_bias[bt*256 + lane*4 + r] = b[ot*16 + (lane>>4)*4 + r].
__global__ void prep_weights(const float* __restrict__ W_ih, const float* __restrict__ b_ih,
                             const float* __restrict__ b_hh,
                             const float* __restrict__ W1, const float* __restrict__ b1,
                             const float* __restrict__ W2, const float* __restrict__ b2,
                             const float* __restrict__ W3, const float* __restrict__ b3,
                             const float* __restrict__ W4, const float* __restrict__ b4)
{
    const int gid = blockIdx.x * blockDim.x + threadIdx.x;
    const int gs  = gridDim.x * blockDim.x;

    for (int i = gid; i < N_FRAG_U32; i += gs) {
        int t = i >> 8, rlo = i & 255;
        int lane = rlo >> 2, j = rlo & 3;
        const float* W; int N, K, ld, ks, nt;
        if (t < 8)       { W = W1; N = 51; K = 34; ld = 34; ks = t >> 2;     nt = t & 3; }
        else if (t < 16) { W = W2; N = 51; K = 51; ld = 51; ks = (t-8) >> 2; nt = (t-8) & 3; }
        else if (t < 22) { W = W3; N = 34; K = 51; ld = 51; ks = (t-16) / 3; nt = (t-16) % 3; }
        else             { W = W4; N = 5;  K = 34; ld = 34; ks = t - 22;     nt = 0; }
        int m = nt * 16 + (lane & 15);
        int k_lo, k_hi;
        if (t < 8) {
            int p = ks * 16 + (lane >> 4) * 4 + j;
            k_lo = 2 * p; k_hi = k_lo + 1;
        } else {
            int q = ks * 32 + (lane >> 4) * 8 + 2 * j;
            k_lo = (2 * (q >> 5) + ((q & 7) >> 2)) * 16 + ((q >> 3) & 3) * 4 + (q & 3);
            int q1 = q + 1;
            k_hi = (2 * (q1 >> 5) + ((q1 & 7) >> 2)) * 16 + ((q1 >> 3) & 3) * 4 + (q1 & 3);
        }
        float a = (m < N && k_lo < K) ? W[m * ld + k_lo] : 0.f;
        float b = (m < N && k_hi < K) ? W[m * ld + k_hi] : 0.f;
        g_frag[i] = as_u32(pk(a, b));
    }
    for (int i = gid; i < N_BIAS; i += gs) {
        int bt = i >> 8, rem = i & 255;
        int lane = rem >> 2, r = rem & 3;
        const float* bv; int N, ot;
        if (bt < 4)       { bv = b1; N = 51; ot = bt; }
        else if (bt < 8)  { bv = b2; N = 51; ot = bt - 4; }
        else if (bt < 11) { bv = b3; N = 34; ot = bt - 8; }
        else              { bv = b4; N = 5;  ot = 0; }
        int n = ot * 16 + (lane >> 4) * 4 + r;
        g_bias[i] = (n < N) ? bv[n] : 0.f;
    }
    for (int i = gid; i < N_LSTM; i += gs) {
        int k = i / 24, cc = i - k * 24;
        float v = 0.f;
        if (k < KSEQ) v = (cc < 16) ? W_ih[k * 16 + cc]
                                    : b_ih[k * 8 + (cc - 16)] + b_hh[k * 8 + (cc - 16)];
        g_lstm[i] = v;
    }
}

// ---- main kernel helpers ----
__device__ __forceinline__ h8 load_frag(int tile, int l) {
    union { uint4 u; h8 h; } u;
    u.u = *(const uint4*)&g_frag[tile * 256 + l * 4];
    return u.h;
}

// L1 B-fragments from the stage0 LDS tile: bf[st][ks] = features at
// k-positions (l>>4)*8+jj of sample st*16+(l&15).  (verified read path)
__device__ __forceinline__ void read_bfrags(h8 (&bf)[4][2], const unsigned* my, int l)
{
    const int c = l & 15, g = l >> 4;
    const int mrd = (c & 7) << 2;                        // swizzle mask, row = c
    #pragma unroll
    for (int st = 0; st < 4; ++st)
      #pragma unroll
      for (int ks = 0; ks < 2; ++ks) {
        int idx = (st * 16 + c) * 32 + ((ks * 16 + g * 4) ^ mrd);
        union { uint4 u; h8 h; } u;
        u.u = *(const uint4*)&my[idx];
        bf[st][ks] = u.h;
      }
}

// Swapped-operand layer: acc[ot][st] = W_tile(ot) . act^T(st); ks=0 MFMA
// consumes the per-row bias fragment directly as C.
template<int NT, int TBASE, int BBASE>
__device__ __forceinline__ void layer_swapped(const h8 (&bf)[4][2], f4 (&acc)[4][4], int l)
{
    #pragma unroll
    for (int ot = 0; ot < NT; ++ot) {                    // ks = 0: C = bias(row)
        f4 bias4 = *(const f4*)&g_bias[(BBASE + ot) * 256 + l * 4];
        h8 af = load_frag(TBASE + ot, l);
        #pragma unroll
        for (int st = 0; st < 4; ++st)
          acc[ot][st] = __builtin_amdgcn_mfma_f32_16x16x32_f16(af, bf[st][0], bias4, 0, 0, 0);
    }
    #pragma unroll
    for (int ot = 0; ot < NT; ++ot) {                    // ks = 1: accumulate
        h8 af = load_frag(TBASE + NT + ot, l);
        #pragma unroll
        for (int st = 0; st < 4; ++st)
          acc[ot][st] = __builtin_amdgcn_mfma_f32_16x16x32_f16(af, bf[st][1], acc[ot][st], 0, 0, 0);
    }
}

// In-register relu+pack to next layer's B-frags under the pi k-permutation:
// b-frag[st][ks] f16 slot jj holds neuron (2ks + (jj>>2))*16 + g*4 + (jj&3)
// = acc[2ks + (jj>>2)][st][jj&3].  Pure lane-local.
template<int NT>
__device__ __forceinline__ void pack_bfrags(const f4 (&acc)[4][4], h8 (&bf)[4][2])
{
    #pragma unroll
    for (int st = 0; st < 4; ++st)
      #pragma unroll
      for (int ks = 0; ks < 2; ++ks) {
        const int o0 = 2 * ks, o1 = 2 * ks + 1;
        union { unsigned u[4]; h8 h; } cvt;
        cvt.u[0] = pkrelu(acc[o0][st][0], acc[o0][st][1]);
        cvt.u[1] = pkrelu(acc[o0][st][2], acc[o0][st][3]);
        if (o1 < NT) {
            cvt.u[2] = pkrelu(acc[o1][st][0], acc[o1][st][1]);
            cvt.u[3] = pkrelu(acc[o1][st][2], acc[o1][st][3]);
        } else {
            cvt.u[2] = 0u; cvt.u[3] = 0u;
        }
        bf[st][ks] = cvt.h;
      }
}

// stage0: write full activation row (row = l), sequential pairs, swizzled
__device__ __forceinline__ void stage0(const unsigned (&cp)[32], unsigned* my, int l)
{
    const int m = (l & 7) << 2;
    #pragma unroll
    for (int ch = 0; ch < 8; ++ch) {
        uint4 q = make_uint4(cp[4*ch], cp[4*ch+1], cp[4*ch+2], cp[4*ch+3]);
        *(uint4*)&my[l * 32 + ((4 * ch) ^ m)] = q;
    }
}

__global__ __launch_bounds__(BLK, 3)
void fused_rnn_mlp(const float* __restrict__ in, float* __restrict__ out, int nrows)
{
    __shared__ unsigned act[WPB * 2048];                 // 8 KB per wave-slice
    const int tid = threadIdx.x;
    const int w = tid >> 6, l = tid & 63;
    unsigned* my = &act[w * 2048];
    const long long rb = (long long)blockIdx.x * BLK;
    if (rb + BLK > nrows) return;
    const long long rw = rb + w * 64;

    // own row (8B-aligned, 136B stride)
    float2 x[17];
    {
        const float2* rp = (const float2*)(in + (rw + l) * 34);
        #pragma unroll
        for (int i = 0; i < 17; ++i) x[i] = rp[i];
    }

    // LSTM heads (scalar-pipe params) -> 11 h-pairs + 6 passthrough pairs
    unsigned cp[32];
    #pragma unroll
    for (int kp = 0; kp < 6; ++kp) {
        u16v c0, c1, c2;
        sload3((const unsigned*)&g_lstm[kp * 48], c0, c1, c2);
        h2 h;
        lstm_one(c0, c1, c2, 0, x[2 * kp], h);
        cp[2 * kp] = as_u32(h);
        if (kp < 5) {
            lstm_one(c0, c1, c2, 24, x[2 * kp + 1], h);
            cp[2 * kp + 1] = as_u32(h);
        }
    }
    #pragma unroll
    for (int t = 0; t < 6; ++t) cp[11 + t] = as_u32(pk(x[11 + t].x, x[11 + t].y));
    #pragma unroll
    for (int t = 17; t < 32; ++t) cp[t] = 0u;            // zero K-tail (NaN-safe)

    stage0(cp, my, l);

    h8 bf[4][2];
    f4 acc[4][4];

    read_bfrags(bf, my, l);                  // L1 B-frags (only LDS round-trip)
    layer_swapped<4, 0, 0>(bf, acc, l);      // L1: 34 -> 51
    pack_bfrags<4>(acc, bf);                 // in-register handoff
    layer_swapped<4, 8, 4>(bf, acc, l);      // L2: 51 -> 51
    pack_bfrags<4>(acc, bf);
    layer_swapped<3, 16, 8>(bf, acc, l);     // L3: 51 -> 34
    pack_bfrags<3>(acc, bf);
    layer_swapped<1, 22, 11>(bf, acc, l);    // L4: 34 -> 5

    // stage PRE-sigmoid f32 (D' transposed: lane holds neurons g*4+r of
    // sample st*16+c) into own (now dead) act region, 9-padded
    {
        const int c = l & 15, g = l >> 4;
        float* po = (float*)my;
        #pragma unroll
        for (int st = 0; st < 4; ++st) {
            const int sample = st * 16 + c;
            #pragma unroll
            for (int r = 0; r < 4; ++r) {
                int n = g * 4 + r;
                if (n < 5) po[sample * 9 + n] = acc[0][st][r];
            }
        }
    }
    __syncthreads();

    // block-wide coalesced store: sigmoid applied here
    const long long ob = rb * 5;
    const float* pact = (const float*)act;
    #pragma unroll
    for (int it = 0; it < 5; ++it) {
        int F   = it * BLK + tid;
        int row = (F * 52429) >> 18;                     // F / 5, exact for F < 2^15
        int cc  = F - row * 5;
        out[ob + F] = sig1(pact[(row >> 6) * 2048 + (row & 63) * 9 + cc]);
    }
}

extern "C" void kernel_launch(void* const* d_in, const int* in_sizes, int n_in,
                              void* d_out, int out_size, void* d_ws, size_t ws_size,
                              hipStream_t stream)
{
    const float* input = (const float*)d_in[0];
    const float* W_ih  = (const float*)d_in[1];
    const float* b_ih  = (const float*)d_in[2];
    const float* b_hh  = (const float*)d_in[3];
    const float* W1    = (const float*)d_in[4];
    const float* b1    = (const float*)d_in[5];
    const float* W2    = (const float*)d_in[6];
    const float* b2    = (const float*)d_in[7];
    const float* W3    = (const float*)d_in[8];
    const float* b3    = (const float*)d_in[9];
    const float* W4    = (const float*)d_in[10];
    const float* b4    = (const float*)d_in[11];
    float* out = (float*)d_out;

    int nrows = in_sizes[0] / 34;
    int grid  = nrows / BLK;

    hipLaunchKernelGGL(prep_weights, dim3(8), dim3(256), 0, stream,
                       W_ih, b_ih, b_hh, W1, b1, W2, b2, W3, b3, W4, b4);
    hipLaunchKernelGGL(fused_rnn_mlp, dim3(grid), dim3(BLK), 0, stream,
                       input, out, nrows);
}

// Round 17
// 52.943 us; speedup vs baseline: 1.2555x; 1.0029x over previous
//
#include <hip/hip_runtime.h>

// Fused LSTM-heads + 4-layer MLP on the MATRIX pipe — SWAPPED-OPERAND form.
// Each layer computes D' = W · act^T  (A = W, B = activations^T); with the
// pi k-permutation applied to BOTH packed activations and next-layer W
// columns, the inter-layer handoff is PURE IN-REGISTER (8 pkrelu/sample-tile).
// Only L1 reads B-frags from the stage0 LDS tile. Bias rides ks=0 MFMA C.
// r17: (a) input rows loaded as 8 x dwordx4 + 1 x dwordx2 (9 VMEM, half the
//          TA sector-splits of 17 x dwordx2; rows 8B-aligned, 4B suffices);
//      (b) per-wave epilogue: each wave stores its own 320 contiguous floats,
//          reads only its own LDS region -> NO __syncthreads.

#define BLK  256
#define WPB  4
#define KSEQ 11

typedef _Float16 h2   __attribute__((ext_vector_type(2)));
typedef _Float16 h8   __attribute__((ext_vector_type(8)));
typedef float    f4   __attribute__((ext_vector_type(4)));
typedef unsigned u16v __attribute__((ext_vector_type(16)));

struct __attribute__((packed, aligned(8))) pf4 { f4 v; };   // align-8 float4 load

#define N_FRAG_U32 6144   // 24 tiles * 64 lanes * 4 u32 (f16 pairs)
#define N_BIAS     3072   // 12 bias-tiles * 64 lanes * 4 rows (f32)
#define N_LSTM     288    // 12 * 24 floats (W_ih 16 + folded bias 8 per k)

__device__ __align__(16) float    g_lstm[N_LSTM];
__device__ __align__(16) unsigned g_frag[N_FRAG_U32];
__device__ __align__(16) float    g_bias[N_BIAS];

__device__ __forceinline__ h2 pk(float a, float b) {
    auto r = __builtin_amdgcn_cvt_pkrtz(a, b);
    union { decltype(r) f; h2 h; } c; c.f = r; return c.h;
}
__device__ __forceinline__ unsigned as_u32(h2 h) {
    union { h2 h; unsigned u; } c; c.h = h; return c.u;
}
__device__ __forceinline__ float uf(unsigned u) {
    union { unsigned u; float f; } c; c.u = u; return c.f;
}
__device__ __forceinline__ unsigned pkrelu(float a, float b) {   // pack then v_pk_max_f16
    h2 p = pk(a, b);
    h2 z = {(_Float16)0.0f, (_Float16)0.0f};
    h2 r = __builtin_elementwise_max(p, z);
    return as_u32(r);
}
__device__ __forceinline__ float fast_exp(float x) {
#if __has_builtin(__builtin_amdgcn_exp2f)
    return __builtin_amdgcn_exp2f(x * 1.44269504088896340736f);
#else
    return __expf(x);
#endif
}
__device__ __forceinline__ float fast_rcp(float x) {
#if __has_builtin(__builtin_amdgcn_rcpf)
    return __builtin_amdgcn_rcpf(x);
#else
    return 1.0f / x;
#endif
}
__device__ __forceinline__ float sig1(float x)  { return fast_rcp(1.0f + fast_exp(-x)); }

// sig(a) * tanh(b) with a single rcp
__device__ __forceinline__ float sigtanh(float a, float b) {
    float ea = fast_exp(-a);
    float eb = fast_exp(2.0f * b);
    return (eb - 1.0f) * fast_rcp((1.0f + ea) * (eb + 1.0f));
}

// scalar-pipe load of 48 u32 (LSTM params for a k-pair); waitcnt fused in-block
__device__ __forceinline__ void sload3(const unsigned* p, u16v& c0, u16v& c1, u16v& c2) {
    asm volatile("s_load_dwordx16 %0, %3, 0x0\n\t"
                 "s_load_dwordx16 %1, %3, 0x40\n\t"
                 "s_load_dwordx16 %2, %3, 0x80\n\t"
                 "s_waitcnt lgkmcnt(0)"
                 : "=&s"(c0), "=&s"(c1), "=&s"(c2) : "s"(p));
}
__device__ __forceinline__ unsigned pick48(const u16v& c0, const u16v& c1, const u16v& c2, int j) {
    return j < 16 ? c0[j] : (j < 32 ? c1[j - 16] : c2[j - 32]);
}

__device__ __forceinline__ void lstm_one(const u16v& c0, const u16v& c1, const u16v& c2, int base,
                                         float2 x, h2& outp)
{
    float w0  = uf(pick48(c0, c1, c2, base + 0)),  w1  = uf(pick48(c0, c1, c2, base + 1));
    float w2  = uf(pick48(c0, c1, c2, base + 2)),  w3  = uf(pick48(c0, c1, c2, base + 3));
    float w8  = uf(pick48(c0, c1, c2, base + 8)),  w9  = uf(pick48(c0, c1, c2, base + 9));
    float w10 = uf(pick48(c0, c1, c2, base + 10)), w11 = uf(pick48(c0, c1, c2, base + 11));
    float w12 = uf(pick48(c0, c1, c2, base + 12)), w13 = uf(pick48(c0, c1, c2, base + 13));
    float w14 = uf(pick48(c0, c1, c2, base + 14)), w15 = uf(pick48(c0, c1, c2, base + 15));
    float B0  = uf(pick48(c0, c1, c2, base + 16)), B1v = uf(pick48(c0, c1, c2, base + 17));
    float B4  = uf(pick48(c0, c1, c2, base + 20)), B5  = uf(pick48(c0, c1, c2, base + 21));
    float B6  = uf(pick48(c0, c1, c2, base + 22)), B7  = uf(pick48(c0, c1, c2, base + 23));

    float x0 = x.x, x1 = x.y;
    float gi0 = B0  + x0 * w0  + x1 * w1;
    float gi1 = B1v + x0 * w2  + x1 * w3;
    float gg0 = B4  + x0 * w8  + x1 * w9;
    float gg1 = B5  + x0 * w10 + x1 * w11;
    float go0 = B6  + x0 * w12 + x1 * w13;
    float go1 = B7  + x0 * w14 + x1 * w15;
    float cc0 = sigtanh(gi0, gg0);
    float cc1 = sigtanh(gi1, gg1);
    float h0  = sigtanh(go0, cc0);
    float h1  = sigtanh(go1, cc1);
    outp = pk(h0, h1);
}

// ---- prep: pack W as A-fragments, per-ROW bias tiles, LSTM params ----
// tile ids: L1: 0..7 = ks*4+nt | L2: 8..15 | L3: 16..21 = 16+ks*3+nt | L4: 22..23
// A-frag: lane holds W[m = nt*16+(lane&15)][k-position (lane>>4)*8 + jj of step ks].
//   L1 (stage0, sequential features): k = 2p, 2p+1 at p = ks*16+(lane>>4)*4+j.
//   L2/L3/L4 (in-register pack): feature at k-position q is
//       pi(q) = (2*(q>>5) + ((q&7)>>2))*16 + ((q>>3)&3)*4 + (q&3).
// bias tiles (per-row): g_bias[bt*256 + lane*4 + r] = b[ot*16 + (lane>>4)*4 + r].
__global__ void prep_weights(const float* __restrict__ W_ih, const float* __restrict__ b_ih,
                             const float* __restrict__ b_hh,
                             const float* __restrict__ W1, const float* __restrict__ b1,
                             const float* __restrict__ W2, const float* __restrict__ b2,
                             const float* __restrict__ W3, const float* __restrict__ b3,
                             const float* __restrict__ W4, const float* __restrict__ b4)
{
    const int gid = blockIdx.x * blockDim.x + threadIdx.x;
    const int gs  = gridDim.x * blockDim.x;

    for (int i = gid; i < N_FRAG_U32; i += gs) {
        int t = i >> 8, rlo = i & 255;
        int lane = rlo >> 2, j = rlo & 3;
        const float* W; int N, K, ld, ks, nt;
        if (t < 8)       { W = W1; N = 51; K = 34; ld = 34; ks = t >> 2;     nt = t & 3; }
        else if (t < 16) { W = W2; N = 51; K = 51; ld = 51; ks = (t-8) >> 2; nt = (t-8) & 3; }
        else if (t < 22) { W = W3; N = 34; K = 51; ld = 51; ks = (t-16) / 3; nt = (t-16) % 3; }
        else             { W = W4; N = 5;  K = 34; ld = 34; ks = t - 22;     nt = 0; }
        int m = nt * 16 + (lane & 15);
        int k_lo, k_hi;
        if (t < 8) {
            int p = ks * 16 + (lane >> 4) * 4 + j;
            k_lo = 2 * p; k_hi = k_lo + 1;
        } else {
            int q = ks * 32 + (lane >> 4) * 8 + 2 * j;
            k_lo = (2 * (q >> 5) + ((q & 7) >> 2)) * 16 + ((q >> 3) & 3) * 4 + (q & 3);
            int q1 = q + 1;
            k_hi = (2 * (q1 >> 5) + ((q1 & 7) >> 2)) * 16 + ((q1 >> 3) & 3) * 4 + (q1 & 3);
        }
        float a = (m < N && k_lo < K) ? W[m * ld + k_lo] : 0.f;
        float b = (m < N && k_hi < K) ? W[m * ld + k_hi] : 0.f;
        g_frag[i] = as_u32(pk(a, b));
    }
    for (int i = gid; i < N_BIAS; i += gs) {
        int bt = i >> 8, rem = i & 255;
        int lane = rem >> 2, r = rem & 3;
        const float* bv; int N, ot;
        if (bt < 4)       { bv = b1; N = 51; ot = bt; }
        else if (bt < 8)  { bv = b2; N = 51; ot = bt - 4; }
        else if (bt < 11) { bv = b3; N = 34; ot = bt - 8; }
        else              { bv = b4; N = 5;  ot = 0; }
        int n = ot * 16 + (lane >> 4) * 4 + r;
        g_bias[i] = (n < N) ? bv[n] : 0.f;
    }
    for (int i = gid; i < N_LSTM; i += gs) {
        int k = i / 24, cc = i - k * 24;
        float v = 0.f;
        if (k < KSEQ) v = (cc < 16) ? W_ih[k * 16 + cc]
                                    : b_ih[k * 8 + (cc - 16)] + b_hh[k * 8 + (cc - 16)];
        g_lstm[i] = v;
    }
}

// ---- main kernel helpers ----
__device__ __forceinline__ h8 load_frag(int tile, int l) {
    union { uint4 u; h8 h; } u;
    u.u = *(const uint4*)&g_frag[tile * 256 + l * 4];
    return u.h;
}

// L1 B-fragments from the stage0 LDS tile (verified read path)
__device__ __forceinline__ void read_bfrags(h8 (&bf)[4][2], const unsigned* my, int l)
{
    const int c = l & 15, g = l >> 4;
    const int mrd = (c & 7) << 2;                        // swizzle mask, row = c
    #pragma unroll
    for (int st = 0; st < 4; ++st)
      #pragma unroll
      for (int ks = 0; ks < 2; ++ks) {
        int idx = (st * 16 + c) * 32 + ((ks * 16 + g * 4) ^ mrd);
        union { uint4 u; h8 h; } u;
        u.u = *(const uint4*)&my[idx];
        bf[st][ks] = u.h;
      }
}

// Swapped-operand layer: acc[ot][st] = W_tile(ot) . act^T(st); ks=0 MFMA
// consumes the per-row bias fragment directly as C.
template<int NT, int TBASE, int BBASE>
__device__ __forceinline__ void layer_swapped(const h8 (&bf)[4][2], f4 (&acc)[4][4], int l)
{
    #pragma unroll
    for (int ot = 0; ot < NT; ++ot) {                    // ks = 0: C = bias(row)
        f4 bias4 = *(const f4*)&g_bias[(BBASE + ot) * 256 + l * 4];
        h8 af = load_frag(TBASE + ot, l);
        #pragma unroll
        for (int st = 0; st < 4; ++st)
          acc[ot][st] = __builtin_amdgcn_mfma_f32_16x16x32_f16(af, bf[st][0], bias4, 0, 0, 0);
    }
    #pragma unroll
    for (int ot = 0; ot < NT; ++ot) {                    // ks = 1: accumulate
        h8 af = load_frag(TBASE + NT + ot, l);
        #pragma unroll
        for (int st = 0; st < 4; ++st)
          acc[ot][st] = __builtin_amdgcn_mfma_f32_16x16x32_f16(af, bf[st][1], acc[ot][st], 0, 0, 0);
    }
}

// In-register relu+pack under the pi k-permutation (pure lane-local)
template<int NT>
__device__ __forceinline__ void pack_bfrags(const f4 (&acc)[4][4], h8 (&bf)[4][2])
{
    #pragma unroll
    for (int st = 0; st < 4; ++st)
      #pragma unroll
      for (int ks = 0; ks < 2; ++ks) {
        const int o0 = 2 * ks, o1 = 2 * ks + 1;
        union { unsigned u[4]; h8 h; } cvt;
        cvt.u[0] = pkrelu(acc[o0][st][0], acc[o0][st][1]);
        cvt.u[1] = pkrelu(acc[o0][st][2], acc[o0][st][3]);
        if (o1 < NT) {
            cvt.u[2] = pkrelu(acc[o1][st][0], acc[o1][st][1]);
            cvt.u[3] = pkrelu(acc[o1][st][2], acc[o1][st][3]);
        } else {
            cvt.u[2] = 0u; cvt.u[3] = 0u;
        }
        bf[st][ks] = cvt.h;
      }
}

// stage0: write full activation row (row = l), sequential pairs, swizzled
__device__ __forceinline__ void stage0(const unsigned (&cp)[32], unsigned* my, int l)
{
    const int m = (l & 7) << 2;
    #pragma unroll
    for (int ch = 0; ch < 8; ++ch) {
        uint4 q = make_uint4(cp[4*ch], cp[4*ch+1], cp[4*ch+2], cp[4*ch+3]);
        *(uint4*)&my[l * 32 + ((4 * ch) ^ m)] = q;
    }
}

__global__ __launch_bounds__(BLK, 3)
void fused_rnn_mlp(const float* __restrict__ in, float* __restrict__ out, int nrows)
{
    __shared__ unsigned act[WPB * 2048];                 // 8 KB per wave-slice
    const int tid = threadIdx.x;
    const int w = tid >> 6, l = tid & 63;
    unsigned* my = &act[w * 2048];
    const long long rb = (long long)blockIdx.x * BLK;
    if (rb + BLK > nrows) return;
    const long long rw = rb + w * 64;

    // own row: 8 x dwordx4 (8B-aligned) + 1 x dwordx2  (9 VMEM vs 17)
    float2 x[17];
    {
        const float* rp = in + (rw + l) * 34;
        #pragma unroll
        for (int q = 0; q < 8; ++q) {
            f4 v = ((const pf4*)(rp))[q].v;
            x[2 * q]     = make_float2(v.x, v.y);
            x[2 * q + 1] = make_float2(v.z, v.w);
        }
        x[16] = *(const float2*)(rp + 32);
    }

    // LSTM heads (scalar-pipe params) -> 11 h-pairs + 6 passthrough pairs
    unsigned cp[32];
    #pragma unroll
    for (int kp = 0; kp < 6; ++kp) {
        u16v c0, c1, c2;
        sload3((const unsigned*)&g_lstm[kp * 48], c0, c1, c2);
        h2 h;
        lstm_one(c0, c1, c2, 0, x[2 * kp], h);
        cp[2 * kp] = as_u32(h);
        if (kp < 5) {
            lstm_one(c0, c1, c2, 24, x[2 * kp + 1], h);
            cp[2 * kp + 1] = as_u32(h);
        }
    }
    #pragma unroll
    for (int t = 0; t < 6; ++t) cp[11 + t] = as_u32(pk(x[11 + t].x, x[11 + t].y));
    #pragma unroll
    for (int t = 17; t < 32; ++t) cp[t] = 0u;            // zero K-tail (NaN-safe)

    stage0(cp, my, l);

    h8 bf[4][2];
    f4 acc[4][4];

    read_bfrags(bf, my, l);                  // L1 B-frags (only LDS round-trip)
    layer_swapped<4, 0, 0>(bf, acc, l);      // L1: 34 -> 51
    pack_bfrags<4>(acc, bf);                 // in-register handoff
    layer_swapped<4, 8, 4>(bf, acc, l);      // L2: 51 -> 51
    pack_bfrags<4>(acc, bf);
    layer_swapped<3, 16, 8>(bf, acc, l);     // L3: 51 -> 34
    pack_bfrags<3>(acc, bf);
    layer_swapped<1, 22, 11>(bf, acc, l);    // L4: 34 -> 5

    // stage PRE-sigmoid f32 (D' transposed: lane holds neurons g*4+r of
    // sample st*16+c) into own (now dead) act region, 9-padded
    {
        const int c = l & 15, g = l >> 4;
        float* po = (float*)my;
        #pragma unroll
        for (int st = 0; st < 4; ++st) {
            const int sample = st * 16 + c;
            #pragma unroll
            for (int r = 0; r < 4; ++r) {
                int n = g * 4 + r;
                if (n < 5) po[sample * 9 + n] = acc[0][st][r];
            }
        }
    }
    // NO __syncthreads: each wave reads back only its OWN region (same-wave
    // LDS RAW is compiler-tracked, as proven by the stage0->read path).

    // per-wave coalesced store: 320 contiguous floats at out + rw*5
    {
        const float* po = (const float*)my;
        const long long ob = rw * 5;
        #pragma unroll
        for (int it = 0; it < 5; ++it) {
            int F   = it * 64 + l;                       // 0..319
            int row = (F * 52429) >> 18;                 // F / 5, exact
            int cc  = F - row * 5;
            out[ob + F] = sig1(po[row * 9 + cc]);
        }
    }
}

extern "C" void kernel_launch(void* const* d_in, const int* in_sizes, int n_in,
                              void* d_out, int out_size, void* d_ws, size_t ws_size,
                              hipStream_t stream)
{
    const float* input = (const float*)d_in[0];
    const float* W_ih  = (const float*)d_in[1];
    const float* b_ih  = (const float*)d_in[2];
    const float* b_hh  = (const float*)d_in[3];
    const float* W1    = (const float*)d_in[4];
    const float* b1    = (const float*)d_in[5];
    const float* W2    = (const float*)d_in[6];
    const float* b2    = (const float*)d_in[7];
    const float* W3    = (const float*)d_in[8];
    const float* b3    = (const float*)d_in[9];
    const float* W4    = (const float*)d_in[10];
    const float* b4    = (const float*)d_in[11];
    float* out = (float*)d_out;

    int nrows = in_sizes[0] / 34;
    int grid  = nrows / BLK;

    hipLaunchKernelGGL(prep_weights, dim3(8), dim3(256), 0, stream,
                       W_ih, b_ih, b_hh, W1, b1, W2, b2, W3, b3, W4, b4);
    hipLaunchKernelGGL(fused_rnn_mlp, dim3(grid), dim3(BLK), 0, stream,
                       input, out, nrows);
}